// Round 10
// baseline (284.607 us; speedup 1.0000x reference)
//
#include <hip/hip_runtime.h>

#define N 6144
#define E 196608
#define EN (E + N)      // 202752
#define LGAT 10
#define HBLK 99         // hist/scatter blocks: 99*256*8 = 202752 = EN
#define GBLK 192        // gat blocks: 192*256/8 = 6144 dsts, 8 lanes each
#define TBLK 192        // tc blocks: 192*256/8 = 6144 dsts, 8 lanes each
#define MCH 768         // MHA m-chunk size (8 chunks)
#define NCH 8           // 6144/768

typedef unsigned int u32;

// order-preserving float<->uint for atomicMax/Min on floats (incl. negatives)
__device__ __forceinline__ u32 f2key(float f) {
    u32 u = __float_as_uint(f);
    return (u & 0x80000000u) ? ~u : (u | 0x80000000u);
}
__device__ __forceinline__ float key2f(u32 k) {
    u32 u = (k & 0x80000000u) ? (k & 0x7FFFFFFFu) : ~k;
    return __uint_as_float(u);
}
// agent(device)-scope coherent loads: read values produced by other blocks'
// atomics WITHIN the same dispatch (tiny data only — bypasses caches).
__device__ __forceinline__ float aload_f(const float* p2) {
    return __hip_atomic_load(p2, __ATOMIC_RELAXED, __HIP_MEMORY_SCOPE_AGENT);
}
__device__ __forceinline__ u32 aload_u(const u32* p2) {
    return __hip_atomic_load(p2, __ATOMIC_RELAXED, __HIP_MEMORY_SCOPE_AGENT);
}

struct P {
    const float *x, *mask, *gat_W, *gat_asrc, *gat_adst, *gat_b;
    const float *in_w, *in_b, *out_w, *out_b;
    const float *Wq, *bq, *Wk, *bk, *Wv, *bv, *Wsk, *bsk;
    const float *W1, *b1, *W2, *b2, *W3, *b3, *cW, *cb;
    const int *src, *dst;
    float4 *nodeA, *nodeB;          // per-node {xp0,xp1,xp2,ssrc}
    float *sdstA, *sdstB;
    float *qkv, *q2, *h2, *h3, *part;
    float4 *kv2;                    // per-node 2x float4 {k0,k1,k2,v0},{v1,v2,_,_}
    float *a1pre, *a2buf, *sumres;
    u32 *deg, *offs, *cursor, *kmaxk, *kmink;
    u32 *kmaxk2, *kmink2;
    u32 *ssmaxk;                    // per-GAT-layer global max of ssrc keys [LGAT]
    u32 *ctr;                       // last-block counters
    int *ssorted;
    float *out;
};

// ---- init: zero everything that gets atomically accumulated ---------------
__global__ void k_init(P p) {
    int t = blockIdx.x * 256 + threadIdx.x;   // 0..6143
    p.deg[t] = 0u;
    if (t < 16) p.a1pre[t] = 0.f;
    else if (t == 16) p.sumres[0] = 0.f;
    else if (t >= 32 && t < 35) { p.kmaxk[t - 32] = 0u; p.kmink[t - 32] = 0xFFFFFFFFu; }
    else if (t >= 35 && t < 38) { p.kmaxk2[t - 35] = 0u; p.kmink2[t - 35] = 0xFFFFFFFFu; }
    else if (t >= 48 && t < 48 + LGAT) p.ssmaxk[t - 48] = 0u;  // key 0 < every float key
    else if (t >= 64 && t < 72) p.ctr[t - 64] = 0u;
}

// ---- CSR: histogram of dst; LAST block runs the exclusive scan ------------
__global__ void k_hist(P p) {
    __shared__ u32 spart[256];
    __shared__ bool last;
    int t = blockIdx.x * 256 + threadIdx.x;   // 0..25343
    #pragma unroll
    for (int k = 0; k < 8; ++k) {
        int e = t + k * (HBLK * 256);
        int d = (e < E) ? p.dst[e] : (e - E);
        atomicAdd(&p.deg[d], 1u);
    }
    __syncthreads();
    if (threadIdx.x == 0) {
        __threadfence();
        last = (atomicAdd(&p.ctr[0], 1u) == HBLK - 1);
    }
    __syncthreads();
    if (!last) return;
    int tid = threadIdx.x;
    u32 loc[24];
    u32 sum = 0;
    #pragma unroll
    for (int i = 0; i < 24; ++i) { loc[i] = sum; sum += aload_u(&p.deg[tid * 24 + i]); }
    spart[tid] = sum;
    __syncthreads();
    for (int o = 1; o < 256; o <<= 1) {
        u32 v = (tid >= o) ? spart[tid - o] : 0u;
        __syncthreads();
        spart[tid] += v;
        __syncthreads();
    }
    u32 base = (tid == 0) ? 0u : spart[tid - 1];
    #pragma unroll
    for (int i = 0; i < 24; ++i) {
        u32 off = base + loc[i];
        p.offs[tid * 24 + i] = off;
        p.cursor[tid * 24 + i] = off;
    }
    if (tid == 255) p.offs[N] = spart[255];
}

// ---- CSR scatter + fused layer-0 node transform ---------------------------
__global__ void k_scatter(P p) {
    int t = blockIdx.x * 256 + threadIdx.x;   // 0..25343
    #pragma unroll
    for (int k = 0; k < 8; ++k) {
        int e = t + k * (HBLK * 256);
        int s = (e < E) ? p.src[e] : (e - E);
        int d = (e < E) ? p.dst[e] : (e - E);
        u32 pos = atomicAdd(&p.cursor[d], 1u);
        p.ssorted[pos] = s;
    }
    if (t < N) {
        float h0 = p.x[t * 3 + 0], h1 = p.x[t * 3 + 1], h2 = p.x[t * 3 + 2];
        const float* W = p.gat_W;
        float xp0 = h0 * W[0] + h1 * W[3] + h2 * W[6];
        float xp1 = h0 * W[1] + h1 * W[4] + h2 * W[7];
        float xp2 = h0 * W[2] + h1 * W[5] + h2 * W[8];
        float ss = xp0 * p.gat_asrc[0] + xp1 * p.gat_asrc[1] + xp2 * p.gat_asrc[2];
        p.nodeA[t] = make_float4(xp0, xp1, xp2, ss);
        p.sdstA[t] = xp0 * p.gat_adst[0] + xp1 * p.gat_adst[1] + xp2 * p.gat_adst[2];
        float m = ss;                          // blocks 0..23 are fully t<N
        #pragma unroll
        for (int o = 32; o; o >>= 1) m = fmaxf(m, __shfl_xor(m, o));
        if ((threadIdx.x & 63) == 0) atomicMax(&p.ssmaxk[0], f2key(m));
    }
}

// ---- GAT edge kernel: 8 lanes/dst, 192 blocks, single-pass softmax --------
// Row max replaced by closed-form upper bound leaky(ssmax_global + sd);
// softmax is shift-invariant so this is exact (gap ~0.1-scale, no underflow).
// l==LGAT-1 epilogue: project to qkv AND fuse global k min/max (for MHA).
__global__ __launch_bounds__(256) void k_gat(P p, const float4* __restrict__ nin,
                                             const float* __restrict__ sdin,
                                             float4* __restrict__ nout,
                                             float* __restrict__ sdout, int l) {
    __shared__ float ssh[32];
    __shared__ float kksh[32][3];
    int gid = blockIdx.x * 256 + threadIdx.x;
    int d = gid >> 3;
    int lane = gid & 7;
    int tid = threadIdx.x;
    u32 beg = p.offs[d], end = p.offs[d + 1];
    float sd = sdin[d];
    float vb = key2f(p.ssmaxk[l]) + sd;
    float M = (vb >= 0.f) ? vb : 0.2f * vb;
    float sz = 0.f, s0 = 0.f, s1 = 0.f, s2 = 0.f;
    for (u32 i = beg + lane; i < end; i += 8) {
        float4 r = nin[p.ssorted[i]];
        float v = r.w + sd;
        v = (v >= 0.f) ? v : 0.2f * v;
        float w = __expf(v - M);
        sz += w; s0 += w * r.x; s1 += w * r.y; s2 += w * r.z;
    }
    #pragma unroll
    for (int o = 1; o < 8; o <<= 1) {
        sz += __shfl_xor(sz, o);
        s0 += __shfl_xor(s0, o);
        s1 += __shfl_xor(s1, o);
        s2 += __shfl_xor(s2, o);
    }
    if (lane == 0) {
        float z = sz + 1e-16f;
        float o0 = s0 / z + p.gat_b[l * 3 + 0];
        float o1 = s1 / z + p.gat_b[l * 3 + 1];
        float o2 = s2 / z + p.gat_b[l * 3 + 2];
        if (l < LGAT - 1) {
            o0 = fmaxf(o0, 0.f); o1 = fmaxf(o1, 0.f); o2 = fmaxf(o2, 0.f);
            const float* W = p.gat_W + (l + 1) * 9;
            float xp0 = o0 * W[0] + o1 * W[3] + o2 * W[6];
            float xp1 = o0 * W[1] + o1 * W[4] + o2 * W[7];
            float xp2 = o0 * W[2] + o1 * W[5] + o2 * W[8];
            const float* as = p.gat_asrc + (l + 1) * 3;
            const float* ad = p.gat_adst + (l + 1) * 3;
            float ss = xp0 * as[0] + xp1 * as[1] + xp2 * as[2];
            nout[d] = make_float4(xp0, xp1, xp2, ss);
            sdout[d] = xp0 * ad[0] + xp1 * ad[1] + xp2 * ad[2];
            ssh[tid >> 3] = ss;
        } else {
            float kk[9];
            #pragma unroll
            for (int j = 0; j < 9; ++j) {
                kk[j] = o0 * p.in_w[j * 3 + 0] + o1 * p.in_w[j * 3 + 1] +
                        o2 * p.in_w[j * 3 + 2] + p.in_b[j];
                p.qkv[d * 9 + j] = kk[j];
            }
            kksh[tid >> 3][0] = kk[3];
            kksh[tid >> 3][1] = kk[4];
            kksh[tid >> 3][2] = kk[5];
        }
    }
    __syncthreads();
    if (l < LGAT - 1) {
        if (tid == 0) {
            float m = ssh[0];
            #pragma unroll
            for (int j = 1; j < 32; ++j) m = fmaxf(m, ssh[j]);
            atomicMax(&p.ssmaxk[l + 1], f2key(m));
        }
    } else {
        if (tid < 3) {
            float mx = -1e30f, mn = 1e30f;
            #pragma unroll
            for (int g = 0; g < 32; ++g) {
                mx = fmaxf(mx, kksh[g][tid]);
                mn = fminf(mn, kksh[g][tid]);
            }
            atomicMax(&p.kmaxk[tid], f2key(mx));
            atomicMin(&p.kmink[tid], f2key(mn));
        }
    }
}

// ---- MHA: rank-1 attention, 8 chunks of 768, planar partial stores --------
__global__ void k_att_partial(P p) {
    __shared__ float4 kvA[MCH];   // {k0,k1,k2,v0}
    __shared__ float2 kvB[MCH];   // {v1,v2}
    int tid = threadIdx.x;
    int chunk = blockIdx.y;
    int mbase = chunk * MCH;
    for (int mm = tid; mm < MCH; mm += 256) {
        const float* qk = p.qkv + (size_t)(mbase + mm) * 9;
        kvA[mm] = make_float4(qk[3], qk[4], qk[5], qk[6]);
        kvB[mm] = make_float2(qk[7], qk[8]);
    }
    __syncthreads();
    int n = blockIdx.x * 256 + tid;
    float q0 = p.qkv[n * 9 + 0], q1 = p.qkv[n * 9 + 1], q2 = p.qkv[n * 9 + 2];
    float kmx0 = key2f(p.kmaxk[0]), kmx1 = key2f(p.kmaxk[1]), kmx2 = key2f(p.kmaxk[2]);
    float kmn0 = key2f(p.kmink[0]), kmn1 = key2f(p.kmink[1]), kmn2 = key2f(p.kmink[2]);
    // exact row max of q*k over ALL m: q>=0 -> q*kmax else q*kmin
    float M0 = (q0 >= 0.f) ? q0 * kmx0 : q0 * kmn0;
    float M1 = (q1 >= 0.f) ? q1 * kmx1 : q1 * kmn1;
    float M2 = (q2 >= 0.f) ? q2 * kmx2 : q2 * kmn2;
    float num0 = 0, den0 = 0, num1 = 0, den1 = 0, num2 = 0, den2 = 0;
    #pragma unroll 4
    for (int mm = 0; mm < MCH; ++mm) {
        float4 a = kvA[mm];
        float2 b = kvB[mm];
        float t0 = __expf(q0 * a.x - M0); den0 += t0; num0 += t0 * a.w;
        float t1 = __expf(q1 * a.y - M1); den1 += t1; num1 += t1 * b.x;
        float t2 = __expf(q2 * a.z - M2); den2 += t2; num2 += t2 * b.y;
    }
    // planar layout part[(chunk*6 + r)*N + n] -> coalesced stores
    float* pp = p.part + (size_t)chunk * 6 * N + n;
    pp[0] = num0; pp[N] = den0; pp[2 * N] = num1;
    pp[3 * N] = den1; pp[4 * N] = num2; pp[5 * N] = den2;
}

// ---- MHA reduce + out-proj + TC q2/kv2 records + k2 min/max ---------------
__global__ void k_att_reduce(P p) {
    int n = blockIdx.x * 256 + threadIdx.x;
    float num[3] = {0.f, 0.f, 0.f}, den[3] = {0.f, 0.f, 0.f};
    #pragma unroll
    for (int c = 0; c < NCH; ++c) {
        const float* pp = p.part + (size_t)c * 6 * N + n;
        #pragma unroll
        for (int hh = 0; hh < 3; ++hh) {
            num[hh] += pp[hh * 2 * N];
            den[hh] += pp[(hh * 2 + 1) * N];
        }
    }
    float o[3];
    #pragma unroll
    for (int hh = 0; hh < 3; ++hh) o[hh] = num[hh] / den[hh];
    float h2v[3];
    #pragma unroll
    for (int c = 0; c < 3; ++c) {
        h2v[c] = p.out_b[c] + o[0] * p.out_w[c * 3 + 0] +
                 o[1] * p.out_w[c * 3 + 1] + o[2] * p.out_w[c * 3 + 2];
        p.h2[n * 3 + c] = h2v[c];
    }
    float q2v[3], k2v[3], v2v[3];
    #pragma unroll
    for (int c = 0; c < 3; ++c) {
        q2v[c] = p.bq[c] + h2v[0] * p.Wq[c] + h2v[1] * p.Wq[3 + c] + h2v[2] * p.Wq[6 + c];
        k2v[c] = p.bk[c] + h2v[0] * p.Wk[c] + h2v[1] * p.Wk[3 + c] + h2v[2] * p.Wk[6 + c];
        v2v[c] = p.bv[c] + h2v[0] * p.Wv[c] + h2v[1] * p.Wv[3 + c] + h2v[2] * p.Wv[6 + c];
        p.q2[n * 3 + c] = q2v[c];
    }
    p.kv2[n * 2 + 0] = make_float4(k2v[0], k2v[1], k2v[2], v2v[0]);
    p.kv2[n * 2 + 1] = make_float4(v2v[1], v2v[2], 0.f, 0.f);
    // per-component global min/max of k2 -> TC logit upper bound
    #pragma unroll
    for (int hh = 0; hh < 3; ++hh) {
        float mx = k2v[hh], mn = k2v[hh];
        #pragma unroll
        for (int o2 = 32; o2; o2 >>= 1) {
            mx = fmaxf(mx, __shfl_xor(mx, o2));
            mn = fminf(mn, __shfl_xor(mn, o2));
        }
        if ((threadIdx.x & 63) == 0) {
            atomicMax(&p.kmaxk2[hh], f2key(mx));
            atomicMin(&p.kmink2[hh], f2key(mn));
        }
    }
}

// ---- TC fused edge kernel: 8 lanes/dst, single-pass softmax ---------------
__global__ __launch_bounds__(256) void k_tc_edge(P p) {
    int gid = blockIdx.x * 256 + threadIdx.x;
    int d = gid >> 3;
    int lane = gid & 7;
    u32 beg = p.offs[d], end = p.offs[d + 1];
    float q0 = p.q2[d * 3 + 0], q1 = p.q2[d * 3 + 1], q2 = p.q2[d * 3 + 2];
    const float RS3 = 0.57735026919f;
    float kx0 = key2f(p.kmaxk2[0]), kx1 = key2f(p.kmaxk2[1]), kx2 = key2f(p.kmaxk2[2]);
    float kn0 = key2f(p.kmink2[0]), kn1 = key2f(p.kmink2[1]), kn2 = key2f(p.kmink2[2]);
    float M = ((q0 >= 0.f ? q0 * kx0 : q0 * kn0) +
               (q1 >= 0.f ? q1 * kx1 : q1 * kn1) +
               (q2 >= 0.f ? q2 * kx2 : q2 * kn2)) * RS3;
    float sz = 0.f, s0 = 0.f, s1 = 0.f, s2 = 0.f;
    for (u32 i = beg + lane; i < end; i += 8) {
        int s = p.ssorted[i];
        float4 ka = p.kv2[s * 2];
        float4 kb = p.kv2[s * 2 + 1];
        float lg = (q0 * ka.x + q1 * ka.y + q2 * ka.z) * RS3;
        float w = __expf(lg - M);
        sz += w;
        s0 += w * ka.w; s1 += w * kb.x; s2 += w * kb.y;
    }
    #pragma unroll
    for (int o = 1; o < 8; o <<= 1) {
        sz += __shfl_xor(sz, o);
        s0 += __shfl_xor(s0, o);
        s1 += __shfl_xor(s1, o);
        s2 += __shfl_xor(s2, o);
    }
    if (lane == 0) {
        float z = sz + 1e-16f;
        float h0 = p.h2[d * 3 + 0], h1 = p.h2[d * 3 + 1], h2 = p.h2[d * 3 + 2];
        float agg[3] = {s0 / z, s1 / z, s2 / z};
        #pragma unroll
        for (int c = 0; c < 3; ++c) {
            p.h3[d * 3 + c] = agg[c] + p.bsk[c] +
                h0 * p.Wsk[c] + h1 * p.Wsk[3 + c] + h2 * p.Wsk[6 + c];
        }
    }
}

// ---- MLP stage 1 (+ fused stage 2 in last block) --------------------------
__global__ void k_mlp1(P p) {
    __shared__ float red[64];   // 4 waves x 16
    __shared__ bool last;
    int t = blockIdx.x * 256 + threadIdx.x;
    int j = t & 15;
    int g = t >> 4;             // 0..1151
    float acc = 0.f;
    #pragma unroll
    for (int k = 0; k < 16; ++k) {
        int r = g + k * 1152;
        acc += p.h3[r] * p.W1[r * 16 + j];
    }
    acc += __shfl_xor(acc, 16);
    acc += __shfl_xor(acc, 32);
    int tid = threadIdx.x;
    if ((tid & 63) < 16) red[(tid >> 6) * 16 + j] = acc;
    __syncthreads();
    if (tid < 16) {
        float s = red[tid] + red[16 + tid] + red[32 + tid] + red[48 + tid];
        atomicAdd(&p.a1pre[tid], s);
    }
    __syncthreads();
    if (tid == 0) {
        __threadfence();
        last = (atomicAdd(&p.ctr[2], 1u) == 71u);
    }
    __syncthreads();
    if (!last) return;
    if (tid < 32) {
        float acc2 = p.b2[tid];
        #pragma unroll
        for (int i = 0; i < 16; ++i) {
            float a1 = fmaxf(aload_f(&p.a1pre[i]) + p.b1[i], 0.f);
            acc2 += a1 * p.W2[i * 32 + tid];
        }
        p.a2buf[tid] = fmaxf(acc2, 0.f);
    }
}

// ---- MLP stage 3 (+ fused value in last block) ----------------------------
__global__ void k_mlp3(P p) {
    __shared__ float a2[32];
    __shared__ bool last;
    int tid = threadIdx.x;
    if (tid < 32) a2[tid] = p.a2buf[tid];
    __syncthreads();
    int n = blockIdx.x * 256 + tid;
    float acc = p.b3[n];
    #pragma unroll
    for (int j = 0; j < 32; ++j) acc += a2[j] * p.W3[(size_t)j * N + n];
    p.out[n] = acc * p.mask[n];
    float s = acc;
    #pragma unroll
    for (int o = 32; o; o >>= 1) s += __shfl_xor(s, o);
    if ((tid & 63) == 0) atomicAdd(p.sumres, s);
    __syncthreads();
    if (tid == 0) {
        __threadfence();
        last = (atomicAdd(&p.ctr[3], 1u) == 23u);
    }
    __syncthreads();
    if (last && tid == 0) {
        float sr = aload_f(p.sumres);
        p.out[N] = p.cW[0] * (sr / (float)N) + p.cb[0];
    }
}

extern "C" void kernel_launch(void* const* d_in, const int* in_sizes, int n_in,
                              void* d_out, int out_size, void* d_ws, size_t ws_size,
                              hipStream_t stream) {
    P p;
    p.x      = (const float*)d_in[0];
    p.mask   = (const float*)d_in[1];
    const int* ei = (const int*)d_in[2];
    p.src = ei; p.dst = ei + E;
    p.gat_W  = (const float*)d_in[3];
    p.gat_asrc = (const float*)d_in[4];
    p.gat_adst = (const float*)d_in[5];
    p.gat_b  = (const float*)d_in[6];
    p.in_w   = (const float*)d_in[7];
    p.in_b   = (const float*)d_in[8];
    p.out_w  = (const float*)d_in[9];
    p.out_b  = (const float*)d_in[10];
    p.Wq = (const float*)d_in[11]; p.bq = (const float*)d_in[12];
    p.Wk = (const float*)d_in[13]; p.bk = (const float*)d_in[14];
    p.Wv = (const float*)d_in[15]; p.bv = (const float*)d_in[16];
    p.Wsk = (const float*)d_in[17]; p.bsk = (const float*)d_in[18];
    p.W1 = (const float*)d_in[19]; p.b1 = (const float*)d_in[20];
    p.W2 = (const float*)d_in[21]; p.b2 = (const float*)d_in[22];
    p.W3 = (const float*)d_in[23]; p.b3 = (const float*)d_in[24];
    p.cW = (const float*)d_in[25]; p.cb = (const float*)d_in[26];

    float* ws = (float*)d_ws;
    p.nodeA   = (float4*)(ws + 0);       // 24576 floats
    p.nodeB   = (float4*)(ws + 24576);   // 24576
    p.sdstA   = ws + 49152;              // 6144
    p.sdstB   = ws + 55296;              // 6144
    p.qkv     = ws + 61440;              // 55296
    p.q2      = ws + 116736;             // 18432
    p.kv2     = (float4*)(ws + 135168);  // 49152
    p.h2      = ws + 184320;             // 18432
    p.h3      = ws + 202752;             // 18432
    p.part    = ws + 221184;             // 8*6*6144 = 294912
    p.a1pre   = ws + 516096;             // 16
    p.a2buf   = ws + 516112;             // 32
    p.sumres  = ws + 516144;             // 1
    p.kmaxk   = (u32*)(ws + 516145);     // 3
    p.kmink   = (u32*)(ws + 516148);     // 3
    p.deg     = (u32*)(ws + 516151);     // 6144
    p.offs    = (u32*)(ws + 522295);     // 6145
    p.cursor  = (u32*)(ws + 528440);     // 6144
    p.ssorted = (int*)(ws + 534584);     // 202752 -> ends 737336
    p.kmaxk2  = (u32*)(ws + 737336);     // 3
    p.kmink2  = (u32*)(ws + 737339);     // 3
    p.ssmaxk  = (u32*)(ws + 737342);     // 10
    p.ctr     = (u32*)(ws + 737352);     // 8 -> ends 737360 (~2.95 MB)
    p.out     = (float*)d_out;

    k_init<<<24, 256, 0, stream>>>(p);
    k_hist<<<HBLK, 256, 0, stream>>>(p);        // + last-block scan
    k_scatter<<<HBLK, 256, 0, stream>>>(p);     // + fused node0
    for (int l = 0; l < LGAT; ++l) {
        const float4* nin = (l & 1) ? p.nodeB : p.nodeA;
        const float*  sdin = (l & 1) ? p.sdstB : p.sdstA;
        float4* nout = (l & 1) ? p.nodeA : p.nodeB;
        float*  sdout = (l & 1) ? p.sdstA : p.sdstB;
        k_gat<<<GBLK, 256, 0, stream>>>(p, nin, sdin, nout, sdout, l);
    }
    k_att_partial<<<dim3(24, NCH), 256, 0, stream>>>(p);
    k_att_reduce<<<24, 256, 0, stream>>>(p);
    k_tc_edge<<<TBLK, 256, 0, stream>>>(p);
    k_mlp1<<<72, 256, 0, stream>>>(p);          // + last-block mlp2
    k_mlp3<<<24, 256, 0, stream>>>(p);          // + last-block value
}

// Round 11
// 267.472 us; speedup vs baseline: 1.0641x; 1.0641x over previous
//
#include <hip/hip_runtime.h>

#define N 6144
#define E 196608
#define EN (E + N)      // 202752
#define LGAT 10
#define HBLK 198        // hist/scatter blocks: 198*256*4 = 202752 = EN
#define GBLK 192        // gat blocks: 192*256/8 = 6144 dsts, 8 lanes each
#define TBLK 384        // tc blocks: 384*256/16 = 6144 dsts, 16 lanes each
#define MCH 192         // MHA m-chunk size (32 chunks)

typedef unsigned int u32;

// order-preserving float<->uint for atomicMax/Min on floats (incl. negatives)
__device__ __forceinline__ u32 f2key(float f) {
    u32 u = __float_as_uint(f);
    return (u & 0x80000000u) ? ~u : (u | 0x80000000u);
}
__device__ __forceinline__ float key2f(u32 k) {
    u32 u = (k & 0x80000000u) ? (k & 0x7FFFFFFFu) : ~k;
    return __uint_as_float(u);
}
// agent(device)-scope coherent loads: read values produced by other blocks'
// atomics WITHIN the same dispatch (tiny data only — bypasses caches).
__device__ __forceinline__ float aload_f(const float* p2) {
    return __hip_atomic_load(p2, __ATOMIC_RELAXED, __HIP_MEMORY_SCOPE_AGENT);
}
__device__ __forceinline__ u32 aload_u(const u32* p2) {
    return __hip_atomic_load(p2, __ATOMIC_RELAXED, __HIP_MEMORY_SCOPE_AGENT);
}

struct P {
    const float *x, *mask, *gat_W, *gat_asrc, *gat_adst, *gat_b;
    const float *in_w, *in_b, *out_w, *out_b;
    const float *Wq, *bq, *Wk, *bk, *Wv, *bv, *Wsk, *bsk;
    const float *W1, *b1, *W2, *b2, *W3, *b3, *cW, *cb;
    const int *src, *dst;
    float4 *nodeA, *nodeB;          // per-node {xp0,xp1,xp2,ssrc}
    float *sdstA, *sdstB;
    float *qkv, *q2, *h2, *h3, *part;
    float4 *kv2;                    // per-node 2x float4 {k0,k1,k2,v0},{v1,v2,_,_}
    float *a1pre, *a2buf, *sumres;
    u32 *deg, *offs, *cursor, *kmaxk, *kmink;
    u32 *kmaxk2, *kmink2;
    u32 *ssmaxk;                    // per-GAT-layer global max of ssrc keys [LGAT]
    u32 *ctr;                       // last-block counters
    int *ssorted;
    float *out;
};

// ---- init: zero everything that gets atomically accumulated ---------------
__global__ void k_init(P p) {
    int t = blockIdx.x * 256 + threadIdx.x;   // 0..6143
    p.deg[t] = 0u;
    if (t < 16) p.a1pre[t] = 0.f;
    else if (t == 16) p.sumres[0] = 0.f;
    else if (t >= 32 && t < 35) { p.kmaxk[t - 32] = 0u; p.kmink[t - 32] = 0xFFFFFFFFu; }
    else if (t >= 35 && t < 38) { p.kmaxk2[t - 35] = 0u; p.kmink2[t - 35] = 0xFFFFFFFFu; }
    else if (t >= 48 && t < 48 + LGAT) p.ssmaxk[t - 48] = 0u;  // key 0 < every float key
    else if (t >= 64 && t < 72) p.ctr[t - 64] = 0u;
}

// ---- CSR: histogram of dst; LAST block runs the exclusive scan ------------
__global__ void k_hist(P p) {
    __shared__ u32 spart[256];
    __shared__ bool last;
    int t = blockIdx.x * 256 + threadIdx.x;   // 0..50687
    #pragma unroll
    for (int k = 0; k < 4; ++k) {
        int e = t + k * (HBLK * 256);
        int d = (e < E) ? p.dst[e] : (e - E);
        atomicAdd(&p.deg[d], 1u);
    }
    __syncthreads();
    if (threadIdx.x == 0) {
        __threadfence();
        last = (atomicAdd(&p.ctr[0], 1u) == HBLK - 1);
    }
    __syncthreads();
    if (!last) return;
    int tid = threadIdx.x;
    u32 loc[24];
    u32 sum = 0;
    #pragma unroll
    for (int i = 0; i < 24; ++i) { loc[i] = sum; sum += aload_u(&p.deg[tid * 24 + i]); }
    spart[tid] = sum;
    __syncthreads();
    for (int o = 1; o < 256; o <<= 1) {
        u32 v = (tid >= o) ? spart[tid - o] : 0u;
        __syncthreads();
        spart[tid] += v;
        __syncthreads();
    }
    u32 base = (tid == 0) ? 0u : spart[tid - 1];
    #pragma unroll
    for (int i = 0; i < 24; ++i) {
        u32 off = base + loc[i];
        p.offs[tid * 24 + i] = off;
        p.cursor[tid * 24 + i] = off;
    }
    if (tid == 255) p.offs[N] = spart[255];
}

// ---- CSR scatter + fused layer-0 node transform ---------------------------
__global__ void k_scatter(P p) {
    int t = blockIdx.x * 256 + threadIdx.x;   // 0..50687
    #pragma unroll
    for (int k = 0; k < 4; ++k) {
        int e = t + k * (HBLK * 256);
        int s = (e < E) ? p.src[e] : (e - E);
        int d = (e < E) ? p.dst[e] : (e - E);
        u32 pos = atomicAdd(&p.cursor[d], 1u);
        p.ssorted[pos] = s;
    }
    if (t < N) {
        float h0 = p.x[t * 3 + 0], h1 = p.x[t * 3 + 1], h2 = p.x[t * 3 + 2];
        const float* W = p.gat_W;
        float xp0 = h0 * W[0] + h1 * W[3] + h2 * W[6];
        float xp1 = h0 * W[1] + h1 * W[4] + h2 * W[7];
        float xp2 = h0 * W[2] + h1 * W[5] + h2 * W[8];
        float ss = xp0 * p.gat_asrc[0] + xp1 * p.gat_asrc[1] + xp2 * p.gat_asrc[2];
        p.nodeA[t] = make_float4(xp0, xp1, xp2, ss);
        p.sdstA[t] = xp0 * p.gat_adst[0] + xp1 * p.gat_adst[1] + xp2 * p.gat_adst[2];
        float m = ss;                          // blocks 0..23 are fully t<N
        #pragma unroll
        for (int o = 32; o; o >>= 1) m = fmaxf(m, __shfl_xor(m, o));
        if ((threadIdx.x & 63) == 0) atomicMax(&p.ssmaxk[0], f2key(m));
    }
}

// ---- GAT edge kernel: 8 lanes/dst, 192 blocks, single-pass softmax --------
// Row max replaced by closed-form upper bound leaky(ssmax_global + sd);
// softmax is shift-invariant so this is exact (gap ~0.1-scale, no underflow).
// l==LGAT-1 epilogue: project to qkv AND fuse global k min/max (for MHA).
__global__ __launch_bounds__(256) void k_gat(P p, const float4* __restrict__ nin,
                                             const float* __restrict__ sdin,
                                             float4* __restrict__ nout,
                                             float* __restrict__ sdout, int l) {
    __shared__ float ssh[32];
    __shared__ float kksh[32][3];
    int gid = blockIdx.x * 256 + threadIdx.x;
    int d = gid >> 3;
    int lane = gid & 7;
    int tid = threadIdx.x;
    u32 beg = p.offs[d], end = p.offs[d + 1];
    float sd = sdin[d];
    float vb = key2f(p.ssmaxk[l]) + sd;
    float M = (vb >= 0.f) ? vb : 0.2f * vb;
    float sz = 0.f, s0 = 0.f, s1 = 0.f, s2 = 0.f;
    for (u32 i = beg + lane; i < end; i += 8) {
        float4 r = nin[p.ssorted[i]];
        float v = r.w + sd;
        v = (v >= 0.f) ? v : 0.2f * v;
        float w = __expf(v - M);
        sz += w; s0 += w * r.x; s1 += w * r.y; s2 += w * r.z;
    }
    #pragma unroll
    for (int o = 1; o < 8; o <<= 1) {
        sz += __shfl_xor(sz, o);
        s0 += __shfl_xor(s0, o);
        s1 += __shfl_xor(s1, o);
        s2 += __shfl_xor(s2, o);
    }
    if (lane == 0) {
        float z = sz + 1e-16f;
        float o0 = s0 / z + p.gat_b[l * 3 + 0];
        float o1 = s1 / z + p.gat_b[l * 3 + 1];
        float o2 = s2 / z + p.gat_b[l * 3 + 2];
        if (l < LGAT - 1) {
            o0 = fmaxf(o0, 0.f); o1 = fmaxf(o1, 0.f); o2 = fmaxf(o2, 0.f);
            const float* W = p.gat_W + (l + 1) * 9;
            float xp0 = o0 * W[0] + o1 * W[3] + o2 * W[6];
            float xp1 = o0 * W[1] + o1 * W[4] + o2 * W[7];
            float xp2 = o0 * W[2] + o1 * W[5] + o2 * W[8];
            const float* as = p.gat_asrc + (l + 1) * 3;
            const float* ad = p.gat_adst + (l + 1) * 3;
            float ss = xp0 * as[0] + xp1 * as[1] + xp2 * as[2];
            nout[d] = make_float4(xp0, xp1, xp2, ss);
            sdout[d] = xp0 * ad[0] + xp1 * ad[1] + xp2 * ad[2];
            ssh[tid >> 3] = ss;
        } else {
            float kk[9];
            #pragma unroll
            for (int j = 0; j < 9; ++j) {
                kk[j] = o0 * p.in_w[j * 3 + 0] + o1 * p.in_w[j * 3 + 1] +
                        o2 * p.in_w[j * 3 + 2] + p.in_b[j];
                p.qkv[d * 9 + j] = kk[j];
            }
            kksh[tid >> 3][0] = kk[3];
            kksh[tid >> 3][1] = kk[4];
            kksh[tid >> 3][2] = kk[5];
        }
    }
    __syncthreads();
    if (l < LGAT - 1) {
        if (tid == 0) {
            float m = ssh[0];
            #pragma unroll
            for (int j = 1; j < 32; ++j) m = fmaxf(m, ssh[j]);
            atomicMax(&p.ssmaxk[l + 1], f2key(m));
        }
    } else {
        if (tid < 3) {
            float mx = -1e30f, mn = 1e30f;
            #pragma unroll
            for (int g = 0; g < 32; ++g) {
                mx = fmaxf(mx, kksh[g][tid]);
                mn = fminf(mn, kksh[g][tid]);
            }
            atomicMax(&p.kmaxk[tid], f2key(mx));
            atomicMin(&p.kmink[tid], f2key(mn));
        }
    }
}

// ---- MHA: rank-1 attention, 32 chunks, planar partial stores --------------
__global__ void k_att_partial(P p) {
    __shared__ float4 kvA[MCH];   // {k0,k1,k2,v0}
    __shared__ float2 kvB[MCH];   // {v1,v2}
    int tid = threadIdx.x;
    int chunk = blockIdx.y;
    int mbase = chunk * MCH;
    for (int mm = tid; mm < MCH; mm += 256) {
        const float* qk = p.qkv + (size_t)(mbase + mm) * 9;
        kvA[mm] = make_float4(qk[3], qk[4], qk[5], qk[6]);
        kvB[mm] = make_float2(qk[7], qk[8]);
    }
    __syncthreads();
    int n = blockIdx.x * 256 + tid;
    float q0 = p.qkv[n * 9 + 0], q1 = p.qkv[n * 9 + 1], q2 = p.qkv[n * 9 + 2];
    float kmx0 = key2f(p.kmaxk[0]), kmx1 = key2f(p.kmaxk[1]), kmx2 = key2f(p.kmaxk[2]);
    float kmn0 = key2f(p.kmink[0]), kmn1 = key2f(p.kmink[1]), kmn2 = key2f(p.kmink[2]);
    // exact row max of q*k over ALL m: q>=0 -> q*kmax else q*kmin
    float M0 = (q0 >= 0.f) ? q0 * kmx0 : q0 * kmn0;
    float M1 = (q1 >= 0.f) ? q1 * kmx1 : q1 * kmn1;
    float M2 = (q2 >= 0.f) ? q2 * kmx2 : q2 * kmn2;
    float num0 = 0, den0 = 0, num1 = 0, den1 = 0, num2 = 0, den2 = 0;
    #pragma unroll 4
    for (int mm = 0; mm < MCH; ++mm) {
        float4 a = kvA[mm];
        float2 b = kvB[mm];
        float t0 = __expf(q0 * a.x - M0); den0 += t0; num0 += t0 * a.w;
        float t1 = __expf(q1 * a.y - M1); den1 += t1; num1 += t1 * b.x;
        float t2 = __expf(q2 * a.z - M2); den2 += t2; num2 += t2 * b.y;
    }
    // planar layout part[(chunk*6 + r)*N + n] -> coalesced stores
    float* pp = p.part + (size_t)chunk * 6 * N + n;
    pp[0] = num0; pp[N] = den0; pp[2 * N] = num1;
    pp[3 * N] = den1; pp[4 * N] = num2; pp[5 * N] = den2;
}

// ---- MHA reduce + out-proj + TC q2/kv2 records + k2 min/max ---------------
__global__ void k_att_reduce(P p) {
    int n = blockIdx.x * 256 + threadIdx.x;
    float num[3] = {0.f, 0.f, 0.f}, den[3] = {0.f, 0.f, 0.f};
    #pragma unroll 4
    for (int c = 0; c < 32; ++c) {
        const float* pp = p.part + (size_t)c * 6 * N + n;
        #pragma unroll
        for (int hh = 0; hh < 3; ++hh) {
            num[hh] += pp[hh * 2 * N];
            den[hh] += pp[(hh * 2 + 1) * N];
        }
    }
    float o[3];
    #pragma unroll
    for (int hh = 0; hh < 3; ++hh) o[hh] = num[hh] / den[hh];
    float h2v[3];
    #pragma unroll
    for (int c = 0; c < 3; ++c) {
        h2v[c] = p.out_b[c] + o[0] * p.out_w[c * 3 + 0] +
                 o[1] * p.out_w[c * 3 + 1] + o[2] * p.out_w[c * 3 + 2];
        p.h2[n * 3 + c] = h2v[c];
    }
    float q2v[3], k2v[3], v2v[3];
    #pragma unroll
    for (int c = 0; c < 3; ++c) {
        q2v[c] = p.bq[c] + h2v[0] * p.Wq[c] + h2v[1] * p.Wq[3 + c] + h2v[2] * p.Wq[6 + c];
        k2v[c] = p.bk[c] + h2v[0] * p.Wk[c] + h2v[1] * p.Wk[3 + c] + h2v[2] * p.Wk[6 + c];
        v2v[c] = p.bv[c] + h2v[0] * p.Wv[c] + h2v[1] * p.Wv[3 + c] + h2v[2] * p.Wv[6 + c];
        p.q2[n * 3 + c] = q2v[c];
    }
    p.kv2[n * 2 + 0] = make_float4(k2v[0], k2v[1], k2v[2], v2v[0]);
    p.kv2[n * 2 + 1] = make_float4(v2v[1], v2v[2], 0.f, 0.f);
    // per-component global min/max of k2 -> TC logit upper bound
    #pragma unroll
    for (int hh = 0; hh < 3; ++hh) {
        float mx = k2v[hh], mn = k2v[hh];
        #pragma unroll
        for (int o2 = 32; o2; o2 >>= 1) {
            mx = fmaxf(mx, __shfl_xor(mx, o2));
            mn = fminf(mn, __shfl_xor(mn, o2));
        }
        if ((threadIdx.x & 63) == 0) {
            atomicMax(&p.kmaxk2[hh], f2key(mx));
            atomicMin(&p.kmink2[hh], f2key(mn));
        }
    }
}

// ---- TC fused edge kernel: 16 lanes/dst, single-pass softmax --------------
__global__ __launch_bounds__(256) void k_tc_edge(P p) {
    int gid = blockIdx.x * 256 + threadIdx.x;
    int d = gid >> 4;
    int lane = gid & 15;
    u32 beg = p.offs[d], end = p.offs[d + 1];
    float q0 = p.q2[d * 3 + 0], q1 = p.q2[d * 3 + 1], q2 = p.q2[d * 3 + 2];
    const float RS3 = 0.57735026919f;
    float kx0 = key2f(p.kmaxk2[0]), kx1 = key2f(p.kmaxk2[1]), kx2 = key2f(p.kmaxk2[2]);
    float kn0 = key2f(p.kmink2[0]), kn1 = key2f(p.kmink2[1]), kn2 = key2f(p.kmink2[2]);
    float M = ((q0 >= 0.f ? q0 * kx0 : q0 * kn0) +
               (q1 >= 0.f ? q1 * kx1 : q1 * kn1) +
               (q2 >= 0.f ? q2 * kx2 : q2 * kn2)) * RS3;
    float sz = 0.f, s0 = 0.f, s1 = 0.f, s2 = 0.f;
    for (u32 i = beg + lane; i < end; i += 16) {
        int s = p.ssorted[i];
        float4 ka = p.kv2[s * 2];
        float4 kb = p.kv2[s * 2 + 1];
        float lg = (q0 * ka.x + q1 * ka.y + q2 * ka.z) * RS3;
        float w = __expf(lg - M);
        sz += w;
        s0 += w * ka.w; s1 += w * kb.x; s2 += w * kb.y;
    }
    #pragma unroll
    for (int o = 1; o < 16; o <<= 1) {
        sz += __shfl_xor(sz, o);
        s0 += __shfl_xor(s0, o);
        s1 += __shfl_xor(s1, o);
        s2 += __shfl_xor(s2, o);
    }
    if (lane == 0) {
        float z = sz + 1e-16f;
        float h0 = p.h2[d * 3 + 0], h1 = p.h2[d * 3 + 1], h2 = p.h2[d * 3 + 2];
        float agg[3] = {s0 / z, s1 / z, s2 / z};
        #pragma unroll
        for (int c = 0; c < 3; ++c) {
            p.h3[d * 3 + c] = agg[c] + p.bsk[c] +
                h0 * p.Wsk[c] + h1 * p.Wsk[3 + c] + h2 * p.Wsk[6 + c];
        }
    }
}

// ---- MLP stage 1 (+ fused stage 2 in last block) --------------------------
__global__ void k_mlp1(P p) {
    __shared__ float red[64];   // 4 waves x 16
    __shared__ bool last;
    int t = blockIdx.x * 256 + threadIdx.x;
    int j = t & 15;
    int g = t >> 4;             // 0..1151
    float acc = 0.f;
    #pragma unroll
    for (int k = 0; k < 16; ++k) {
        int r = g + k * 1152;
        acc += p.h3[r] * p.W1[r * 16 + j];
    }
    acc += __shfl_xor(acc, 16);
    acc += __shfl_xor(acc, 32);
    int tid = threadIdx.x;
    if ((tid & 63) < 16) red[(tid >> 6) * 16 + j] = acc;
    __syncthreads();
    if (tid < 16) {
        float s = red[tid] + red[16 + tid] + red[32 + tid] + red[48 + tid];
        atomicAdd(&p.a1pre[tid], s);
    }
    __syncthreads();
    if (tid == 0) {
        __threadfence();
        last = (atomicAdd(&p.ctr[2], 1u) == 71u);
    }
    __syncthreads();
    if (!last) return;
    if (tid < 32) {
        float acc2 = p.b2[tid];
        #pragma unroll
        for (int i = 0; i < 16; ++i) {
            float a1 = fmaxf(aload_f(&p.a1pre[i]) + p.b1[i], 0.f);
            acc2 += a1 * p.W2[i * 32 + tid];
        }
        p.a2buf[tid] = fmaxf(acc2, 0.f);
    }
}

// ---- MLP stage 3 (+ fused value in last block) ----------------------------
__global__ void k_mlp3(P p) {
    __shared__ float a2[32];
    __shared__ bool last;
    int tid = threadIdx.x;
    if (tid < 32) a2[tid] = p.a2buf[tid];
    __syncthreads();
    int n = blockIdx.x * 256 + tid;
    float acc = p.b3[n];
    #pragma unroll
    for (int j = 0; j < 32; ++j) acc += a2[j] * p.W3[(size_t)j * N + n];
    p.out[n] = acc * p.mask[n];
    float s = acc;
    #pragma unroll
    for (int o = 32; o; o >>= 1) s += __shfl_xor(s, o);
    if ((tid & 63) == 0) atomicAdd(p.sumres, s);
    __syncthreads();
    if (tid == 0) {
        __threadfence();
        last = (atomicAdd(&p.ctr[3], 1u) == 23u);
    }
    __syncthreads();
    if (last && tid == 0) {
        float sr = aload_f(p.sumres);
        p.out[N] = p.cW[0] * (sr / (float)N) + p.cb[0];
    }
}

extern "C" void kernel_launch(void* const* d_in, const int* in_sizes, int n_in,
                              void* d_out, int out_size, void* d_ws, size_t ws_size,
                              hipStream_t stream) {
    P p;
    p.x      = (const float*)d_in[0];
    p.mask   = (const float*)d_in[1];
    const int* ei = (const int*)d_in[2];
    p.src = ei; p.dst = ei + E;
    p.gat_W  = (const float*)d_in[3];
    p.gat_asrc = (const float*)d_in[4];
    p.gat_adst = (const float*)d_in[5];
    p.gat_b  = (const float*)d_in[6];
    p.in_w   = (const float*)d_in[7];
    p.in_b   = (const float*)d_in[8];
    p.out_w  = (const float*)d_in[9];
    p.out_b  = (const float*)d_in[10];
    p.Wq = (const float*)d_in[11]; p.bq = (const float*)d_in[12];
    p.Wk = (const float*)d_in[13]; p.bk = (const float*)d_in[14];
    p.Wv = (const float*)d_in[15]; p.bv = (const float*)d_in[16];
    p.Wsk = (const float*)d_in[17]; p.bsk = (const float*)d_in[18];
    p.W1 = (const float*)d_in[19]; p.b1 = (const float*)d_in[20];
    p.W2 = (const float*)d_in[21]; p.b2 = (const float*)d_in[22];
    p.W3 = (const float*)d_in[23]; p.b3 = (const float*)d_in[24];
    p.cW = (const float*)d_in[25]; p.cb = (const float*)d_in[26];

    float* ws = (float*)d_ws;
    p.nodeA   = (float4*)(ws + 0);       // 24576 floats
    p.nodeB   = (float4*)(ws + 24576);   // 24576
    p.sdstA   = ws + 49152;              // 6144
    p.sdstB   = ws + 55296;              // 6144
    p.qkv     = ws + 61440;              // 55296
    p.q2      = ws + 116736;             // 18432
    p.kv2     = (float4*)(ws + 135168);  // 49152
    p.h2      = ws + 184320;             // 18432
    p.h3      = ws + 202752;             // 18432
    p.part    = ws + 221184;             // 32*6*6144 = 1179648
    p.a1pre   = ws + 1400832;            // 16
    p.a2buf   = ws + 1400848;            // 32
    p.sumres  = ws + 1400880;            // 1
    p.kmaxk   = (u32*)(ws + 1400884);    // 3
    p.kmink   = (u32*)(ws + 1400887);    // 3
    p.deg     = (u32*)(ws + 1400890);    // 6144
    p.offs    = (u32*)(ws + 1407034);    // 6145
    p.cursor  = (u32*)(ws + 1413179);    // 6144
    p.ssorted = (int*)(ws + 1419323);    // 202752 -> ends 1622075
    p.kmaxk2  = (u32*)(ws + 1622075);    // 3
    p.kmink2  = (u32*)(ws + 1622078);    // 3
    p.ssmaxk  = (u32*)(ws + 1622081);    // 10
    p.ctr     = (u32*)(ws + 1622091);    // 8 -> ends 1622099 (~6.49 MB)
    p.out     = (float*)d_out;

    k_init<<<24, 256, 0, stream>>>(p);
    k_hist<<<HBLK, 256, 0, stream>>>(p);        // + last-block scan
    k_scatter<<<HBLK, 256, 0, stream>>>(p);     // + fused node0
    for (int l = 0; l < LGAT; ++l) {
        const float4* nin = (l & 1) ? p.nodeB : p.nodeA;
        const float*  sdin = (l & 1) ? p.sdstB : p.sdstA;
        float4* nout = (l & 1) ? p.nodeA : p.nodeB;
        float*  sdout = (l & 1) ? p.sdstA : p.sdstB;
        k_gat<<<GBLK, 256, 0, stream>>>(p, nin, sdin, nout, sdout, l);
    }
    k_att_partial<<<dim3(24, 32), 256, 0, stream>>>(p);
    k_att_reduce<<<24, 256, 0, stream>>>(p);
    k_tc_edge<<<TBLK, 256, 0, stream>>>(p);
    k_mlp1<<<72, 256, 0, stream>>>(p);          // + last-block mlp2
    k_mlp3<<<24, 256, 0, stream>>>(p);          // + last-block value
}